// Round 15
// baseline (843.999 us; speedup 1.0000x reference)
//
#include <hip/hip_runtime.h>
#include <hip/hip_bf16.h>
#include <math.h>

// v15: single-kernel with v11's proven fused structure.
// 128-row / 16-wave blocks (halved weight-L2 stream), L0 = 12 x BK64 steps
// staging x fp32 via 2x global_load_lds (dbuf aliased into act) + enc step 12
// from a 16 KB swizzled LDS buffer; K1..L3 = barrier-free register-ping-pong
// kloops (v10/v11-proven). No H0 round-trip, no serial prep.

#define T_SIZE 524288   // 2^19
#define T_MASK (T_SIZE - 1)

typedef _Float16 f16;
typedef _Float16 f16x8 __attribute__((ext_vector_type(8)));
typedef _Float16 f16x4 __attribute__((ext_vector_type(4)));
typedef float f32x4 __attribute__((ext_vector_type(4)));

struct Scales { float s[16]; };

#define GLD16(gsrc, ldst) __builtin_amdgcn_global_load_lds( \
    (const __attribute__((address_space(1))) void*)(gsrc),  \
    (__attribute__((address_space(3))) void*)(ldst), 16, 0, 0)

// ---------------- weight -> fragment-linear f16 ----------------
// Wf[frag][lane][8]: frag = nblk*(K/32)+ks; (lane,j) = W[ks*32+(lane>>4)*8+j][nblk*16+(lane&15)]
__global__ void wfrag(const float* __restrict__ W, f16* __restrict__ Wf, int K, int N) {
  int tid = blockIdx.x * 256 + threadIdx.x;
  int lane = tid & 63, frag = tid >> 6;
  int KS = K >> 5;
  int nblk = frag / KS, ks = frag - nblk * KS;
  if (nblk * 16 >= N) return;
  int n = nblk * 16 + (lane & 15);
  int kb = ks * 32 + (lane >> 4) * 8;
  f16x8 v;
#pragma unroll
  for (int j = 0; j < 8; ++j) v[j] = (f16)W[(size_t)(kb + j) * N + n];
  *(f16x8*)(Wf + (size_t)frag * 512 + lane * 8) = v;
}

__device__ __forceinline__ float silu_f(float v) {
  return v * __builtin_amdgcn_rcpf(1.f + __expf(-v));
}

__device__ __forceinline__ f16x8 cvt8(f32x4 a, f32x4 b) {
  return (f16x8){ (f16)a.x, (f16)a.y, (f16)a.z, (f16)a.w,
                  (f16)b.x, (f16)b.y, (f16)b.z, (f16)b.w };
}

// K=512 LDS-act main loop, ping-pong weight prefetch (v10-proven, at floor).
template<int NF, int KSTEPS>
__device__ __forceinline__ void kloop_dp(
    const f16* __restrict__ actS, const f16* __restrict__ Wf, int fragRow0,
    int l16, int lhi, int lane, f32x4 (&acc)[4][4]) {
#pragma unroll
  for (int mi = 0; mi < 4; ++mi)
#pragma unroll
    for (int ni = 0; ni < NF; ++ni) acc[mi][ni] = (f32x4){0.f, 0.f, 0.f, 0.f};

  f16x8 bfU[NF], bfV[NF];
  const f16* wbase = Wf + ((size_t)fragRow0 * KSTEPS) * 512 + lane * 8;
#pragma unroll
  for (int ni = 0; ni < NF; ++ni)
    bfU[ni] = *(const f16x8*)(wbase + (size_t)(ni * KSTEPS + 0) * 512);
#pragma unroll
  for (int ni = 0; ni < NF; ++ni)
    bfV[ni] = *(const f16x8*)(wbase + (size_t)(ni * KSTEPS + 1) * 512);

#pragma unroll 1
  for (int ks = 0; ks < KSTEPS; ks += 2) {
    f16x8 af[4];
#pragma unroll
    for (int mi = 0; mi < 4; ++mi) {
      int r = mi * 16 + l16;
      af[mi] = *(const f16x8*)(actS + r * 512 + ((ks * 32 + lhi * 8) ^ ((r & 7) << 3)));
    }
#pragma unroll
    for (int mi = 0; mi < 4; ++mi)
#pragma unroll
      for (int ni = 0; ni < NF; ++ni)
        acc[mi][ni] = __builtin_amdgcn_mfma_f32_16x16x32_f16(bfU[ni], af[mi], acc[mi][ni], 0, 0, 0);
    if (ks + 2 < KSTEPS) {
#pragma unroll
      for (int ni = 0; ni < NF; ++ni)
        bfU[ni] = *(const f16x8*)(wbase + (size_t)(ni * KSTEPS + ks + 2) * 512);
    }
#pragma unroll
    for (int mi = 0; mi < 4; ++mi) {
      int r = mi * 16 + l16;
      af[mi] = *(const f16x8*)(actS + r * 512 + (((ks + 1) * 32 + lhi * 8) ^ ((r & 7) << 3)));
    }
#pragma unroll
    for (int mi = 0; mi < 4; ++mi)
#pragma unroll
      for (int ni = 0; ni < NF; ++ni)
        acc[mi][ni] = __builtin_amdgcn_mfma_f32_16x16x32_f16(bfV[ni], af[mi], acc[mi][ni], 0, 0, 0);
    if (ks + 3 < KSTEPS) {
#pragma unroll
      for (int ni = 0; ni < NF; ++ni)
        bfV[ni] = *(const f16x8*)(wbase + (size_t)(ni * KSTEPS + ks + 3) * 512);
    }
  }
}

// ---------------- fused MLP ----------------
// block = 128 rows, 16 waves (wr = wave>>3 row-half, wc = wave&7 col group).
__global__ __launch_bounds__(1024, 4) void fused_mlp(
    const float* __restrict__ x, const float* __restrict__ t,
    const float* __restrict__ cond, const float* __restrict__ tables,
    const f16* __restrict__ Wf0, const f16* __restrict__ Wf1,
    const f16* __restrict__ Wf2, const f16* __restrict__ Wf3,
    const float* __restrict__ b0, const float* __restrict__ b1,
    const float* __restrict__ b2, const float* __restrict__ b3,
    float* __restrict__ outp, Scales scl) {
  __shared__ f16 act[128 * 512];   // 128 KB, swizzled: r*512 + (c ^ ((r&7)<<3))
  __shared__ f16 encs[128 * 64];   // 16 KB enc buffer, 16B-chunk swizzle
  char* stg = (char*)act;          // L0 fp32 staging alias: [2][32768] B
                                   // within buf: row r (0..127) * 256 B, chunk c4 (0..15) * 16 B

  const int tid = threadIdx.x;
  const int wave = tid >> 6, lane = tid & 63;
  const int l16 = lane & 15, lhi = lane >> 4;
  const int wr = wave >> 3, wc = wave & 7;
  const int rowBase = blockIdx.x * 128;

  // ---- hash-grid encode: thread (sr, c8) -> levels 2c8, 2c8+1 of row sr ----
  {
    const int sr = tid >> 3, c8 = tid & 7;
    int row = rowBase + sr;
    float c0 = cond[2 * row], c1 = cond[2 * row + 1], c2 = t[row];
    unsigned idx[2][8];
    float    wcw[2][8];
#pragma unroll
    for (int d = 0; d < 2; ++d) {
      int l = c8 * 2 + d;
      float s = scl.s[l];
      float xf0 = c0 * s, xf1 = c1 * s, xf2 = c2 * s;
      float xl0 = floorf(xf0), xl1 = floorf(xf1), xl2 = floorf(xf2);
      float w0 = xf0 - xl0, w1 = xf1 - xl1, w2 = xf2 - xl2;
      unsigned xi0 = (unsigned)xl0, xi1 = (unsigned)xl1, xi2 = (unsigned)xl2;
      unsigned h0 = xi0, h1 = xi1 * 2654435761u, h2 = xi2 * 805459861u;
      unsigned g0 = xi0 + 1u, g1 = (xi1 + 1u) * 2654435761u, g2 = (xi2 + 1u) * 805459861u;
#pragma unroll
      for (int c = 0; c < 8; ++c) {
        unsigned ax = (c >> 2) & 1u, ay = (c >> 1) & 1u, az = c & 1u;
        unsigned hh = (ax ? g0 : h0) ^ (ay ? g1 : h1) ^ (az ? g2 : h2);
        idx[d][c] = hh & T_MASK;
        wcw[d][c] = (ax ? w0 : 1.f - w0) * (ay ? w1 : 1.f - w1) * (az ? w2 : 1.f - w2);
      }
    }
    const f32x4* tl0 = (const f32x4*)tables + (size_t)(c8 * 2) * T_SIZE;
    f32x4 fv[2][8];
#pragma unroll
    for (int d = 0; d < 2; ++d)
#pragma unroll
      for (int c = 0; c < 8; ++c)
        fv[d][c] = tl0[(size_t)d * T_SIZE + idx[d][c]];
    f16x8 er;
#pragma unroll
    for (int d = 0; d < 2; ++d) {
      float a0 = 0.f, a1 = 0.f, a2 = 0.f, a3 = 0.f;
#pragma unroll
      for (int c = 0; c < 8; ++c) {
        a0 += wcw[d][c] * fv[d][c].x; a1 += wcw[d][c] * fv[d][c].y;
        a2 += wcw[d][c] * fv[d][c].z; a3 += wcw[d][c] * fv[d][c].w;
      }
      er[d * 4 + 0] = (f16)a0; er[d * 4 + 1] = (f16)a1;
      er[d * 4 + 2] = (f16)a2; er[d * 4 + 3] = (f16)a3;
    }
    // 16B chunk c8 of row sr stored at chunk c8^(sr&7)
    *(f16x8*)(encs + sr * 64 + ((c8 ^ (sr & 7)) * 8)) = er;
  }

  f32x4 acc[4][4];
#pragma unroll
  for (int mi = 0; mi < 4; ++mi)
#pragma unroll
    for (int ni = 0; ni < 4; ++ni) acc[mi][ni] = (f32x4){0.f, 0.f, 0.f, 0.f};

  // ===== Layer 0: 12 x BK64 fp32 GLD16 steps + enc step 12 ====================
  {
    // staging: issue j (0,1) covers rows j*64 + wave*4 + lhi, chunk c4 = l16;
    // global chunk g = c4 ^ (r&15), r&15 = (wave*4+lhi)&15.
    const int srow = wave * 4 + lhi;
    const int gch = l16 ^ (srow & 15);
    const float* xs0 = x + (size_t)(rowBase + srow) * 768 + gch * 4;
    const float* xs1 = x + (size_t)(rowBase + 64 + srow) * 768 + gch * 4;

    GLD16(xs0, stg + wave * 1024);
    GLD16(xs1, stg + 16384 + wave * 1024);
    __syncthreads();   // drains stage 0, publishes encs

#pragma unroll 1
    for (int s = 0; s < 13; ++s) {
      if (s < 11) {
        char* d = stg + ((s + 1) & 1) * 32768 + wave * 1024;
        GLD16(xs0 + (s + 1) * 64, d);
        GLD16(xs1 + (s + 1) * 64, d + 16384);
      }
      f16x8 bf[2][4];
#pragma unroll
      for (int kk = 0; kk < 2; ++kk)
#pragma unroll
        for (int ni = 0; ni < 4; ++ni)
          bf[kk][ni] = *(const f16x8*)(Wf0 + (size_t)((wc * 4 + ni) * 26 + 2 * s + kk) * 512 + lane * 8);

      if (s < 12) {
        const char* rb = stg + (s & 1) * 32768;
#pragma unroll
        for (int kk = 0; kk < 2; ++kk)
#pragma unroll
          for (int mi = 0; mi < 4; ++mi) {
            int r = wr * 64 + mi * 16 + l16;          // r&15 == l16
            const char* rowb = rb + r * 256;
            int c0i = (kk * 8 + lhi * 2) ^ l16;
            f32x4 a = *(const f32x4*)(rowb + c0i * 16);
            f32x4 b = *(const f32x4*)(rowb + (c0i ^ 1) * 16);
            f16x8 af = cvt8(a, b);
#pragma unroll
            for (int ni = 0; ni < 4; ++ni)
              acc[mi][ni] = __builtin_amdgcn_mfma_f32_16x16x32_f16(bf[kk][ni], af, acc[mi][ni], 0, 0, 0);
          }
      } else {  // enc step
#pragma unroll
        for (int kk = 0; kk < 2; ++kk)
#pragma unroll
          for (int mi = 0; mi < 4; ++mi) {
            int r = wr * 64 + mi * 16 + l16;
            f16x8 af = *(const f16x8*)(encs + r * 64 + (((kk * 4 + lhi) ^ (r & 7)) * 8));
#pragma unroll
            for (int ni = 0; ni < 4; ++ni)
              acc[mi][ni] = __builtin_amdgcn_mfma_f32_16x16x32_f16(bf[kk][ni], af, acc[mi][ni], 0, 0, 0);
          }
      }
      __syncthreads();
    }
  }

  // epilogue -> act (bias + silu). D-frag (swapped): row = wr*64 + mi*16 + l16,
  // cols = wc*64 + ni*16 + lhi*4 .. +3
  auto epi_act = [&](const float* __restrict__ bias) {
    __syncthreads();
#pragma unroll
    for (int mi = 0; mi < 4; ++mi) {
      const int row = wr * 64 + mi * 16 + l16;
#pragma unroll
      for (int ni = 0; ni < 4; ++ni) {
        const int col = wc * 64 + ni * 16 + lhi * 4;
        float4 bv = *(const float4*)(bias + col);
        f16x4 o;
        o[0] = (f16)silu_f(acc[mi][ni][0] + bv.x);
        o[1] = (f16)silu_f(acc[mi][ni][1] + bv.y);
        o[2] = (f16)silu_f(acc[mi][ni][2] + bv.z);
        o[3] = (f16)silu_f(acc[mi][ni][3] + bv.w);
        *(f16x4*)(act + row * 512 + (col ^ ((row & 7) << 3))) = o;
      }
    }
    __syncthreads();
  };
  epi_act(b0);

  const f16* actW = act + wr * 64 * 512;   // wave's 64-row half (row&7 preserved)

  // ================= Layers 1,2: K=512 =================
  kloop_dp<4, 16>(actW, Wf1, wc * 4, l16, lhi, lane, acc); epi_act(b1);
  kloop_dp<4, 16>(actW, Wf2, wc * 4, l16, lhi, lane, acc); epi_act(b2);

  // ================= Layer 3 pass A: cols 0..511 =================
  kloop_dp<4, 16>(actW, Wf3, wc * 4, l16, lhi, lane, acc);
#pragma unroll
  for (int mi = 0; mi < 4; ++mi) {
    const size_t row = (size_t)(rowBase + wr * 64 + mi * 16 + l16);
#pragma unroll
    for (int ni = 0; ni < 4; ++ni) {
      const int col = wc * 64 + ni * 16 + lhi * 4;
      float4 bv = *(const float4*)(b3 + col);
      f32x4 o = { acc[mi][ni][0] + bv.x, acc[mi][ni][1] + bv.y,
                  acc[mi][ni][2] + bv.z, acc[mi][ni][3] + bv.w };
      __builtin_nontemporal_store(o, (f32x4*)(outp + row * 768 + col));
    }
  }

  // ================= Layer 3 pass B: cols 512..767 =================
  kloop_dp<2, 16>(actW, Wf3, 32 + wc * 2, l16, lhi, lane, acc);
#pragma unroll
  for (int mi = 0; mi < 4; ++mi) {
    const size_t row = (size_t)(rowBase + wr * 64 + mi * 16 + l16);
#pragma unroll
    for (int ni = 0; ni < 2; ++ni) {
      const int col = 512 + wc * 32 + ni * 16 + lhi * 4;
      float4 bv = *(const float4*)(b3 + col);
      f32x4 o = { acc[mi][ni][0] + bv.x, acc[mi][ni][1] + bv.y,
                  acc[mi][ni][2] + bv.z, acc[mi][ni][3] + bv.w };
      __builtin_nontemporal_store(o, (f32x4*)(outp + row * 768 + col));
    }
  }
}

// ---------------- launch ----------------
extern "C" void kernel_launch(void* const* d_in, const int* in_sizes, int n_in,
                              void* d_out, int out_size, void* d_ws, size_t ws_size,
                              hipStream_t stream) {
  const float* t    = (const float*)d_in[0];
  const float* x    = (const float*)d_in[1];
  const float* cond = (const float*)d_in[2];
  const float* tab  = (const float*)d_in[3];
  const float* W0   = (const float*)d_in[4];
  const float* b0   = (const float*)d_in[5];
  const float* W1   = (const float*)d_in[6];
  const float* b1   = (const float*)d_in[7];
  const float* W2   = (const float*)d_in[8];
  const float* b2   = (const float*)d_in[9];
  const float* W3   = (const float*)d_in[10];
  const float* b3   = (const float*)d_in[11];
  float* out = (float*)d_out;
  (void)in_sizes; (void)n_in; (void)out_size; (void)ws_size;

  char* ws = (char*)d_ws;
  f16* Wf0 = (f16*)(ws + 0);            // 832*512*2 = 851968
  f16* Wf1 = (f16*)(ws + 851968);       // 524288
  f16* Wf2 = (f16*)(ws + 1376256);      // 524288
  f16* Wf3 = (f16*)(ws + 1900544);      // 786432 ; end 2686976

  wfrag<<<dim3(208), 256, 0, stream>>>(W0, Wf0, 832, 512);
  wfrag<<<dim3(128), 256, 0, stream>>>(W1, Wf1, 512, 512);
  wfrag<<<dim3(128), 256, 0, stream>>>(W2, Wf2, 512, 512);
  wfrag<<<dim3(192), 256, 0, stream>>>(W3, Wf3, 512, 768);

  Scales sc;
  {
    double growth = exp((log(512.0) - log(16.0)) / 15.0);
    for (int l = 0; l < 16; ++l) sc.s[l] = (float)floor(16.0 * pow(growth, (double)l));
  }

  fused_mlp<<<dim3(512), 1024, 0, stream>>>(x, t, cond, tab, Wf0, Wf1, Wf2, Wf3,
                                            b0, b1, b2, b3, out, sc);
}

// Round 16
// 291.952 us; speedup vs baseline: 2.8909x; 2.8909x over previous
//
#include <hip/hip_runtime.h>
#include <hip/hip_bf16.h>
#include <math.h>

// v16 = v10 (champion, 291us) restored verbatim.
// Fully-fused hash-encode + 4-layer MLP: 64-row / 8-wave blocks (2 blocks/CU),
// enc batched addr-gen -> 16x loads -> accumulate; L0 = 13 x BK64 steps with
// LDS staging (aliased into act) + dist-2 x-prefetch register pipeline;
// K1..L3 = barrier-free register-ping-pong kloops; swapped-operand MFMA
// epilogues with f16x4/f32x4 vector stores; nontemporal x/out streams.

#define T_SIZE 524288   // 2^19
#define T_MASK (T_SIZE - 1)

typedef _Float16 f16;
typedef _Float16 f16x8 __attribute__((ext_vector_type(8)));
typedef _Float16 f16x4 __attribute__((ext_vector_type(4)));
typedef float f32x4 __attribute__((ext_vector_type(4)));

struct Scales { float s[16]; };

// ---------------- weight -> fragment-linear f16 ----------------
// Wf[frag][lane][8]: frag = nblk*(K/32)+ks32; (lane,j) = W[ks32*32+(lane>>4)*8+j][nblk*16+(lane&15)]
__global__ void wfrag(const float* __restrict__ W, f16* __restrict__ Wf, int K, int N) {
  int tid = blockIdx.x * 256 + threadIdx.x;
  int lane = tid & 63, frag = tid >> 6;
  int KS = K >> 5;
  int nblk = frag / KS, ks = frag - nblk * KS;
  if (nblk * 16 >= N) return;
  int n = nblk * 16 + (lane & 15);
  int kb = ks * 32 + (lane >> 4) * 8;
  f16x8 v;
#pragma unroll
  for (int j = 0; j < 8; ++j) v[j] = (f16)W[(size_t)(kb + j) * N + n];
  *(f16x8*)(Wf + (size_t)frag * 512 + lane * 8) = v;
}

__device__ __forceinline__ float silu_f(float v) {
  return v * __builtin_amdgcn_rcpf(1.f + __expf(-v));
}

__device__ __forceinline__ f16x8 cvt8(f32x4 a, f32x4 b) {
  return (f16x8){ (f16)a.x, (f16)a.y, (f16)a.z, (f16)a.w,
                  (f16)b.x, (f16)b.y, (f16)b.z, (f16)b.w };
}

// K=512 main loop, deep-prefetch ping-pong (distance 2).
template<int NF, int KSTEPS>
__device__ __forceinline__ void kloop_dp(
    const f16* __restrict__ actS, const f16* __restrict__ Wf, int fragRow0,
    int l16, int lhi, int lane, f32x4 (&acc)[4][4]) {
#pragma unroll
  for (int mi = 0; mi < 4; ++mi)
#pragma unroll
    for (int ni = 0; ni < NF; ++ni) acc[mi][ni] = (f32x4){0.f, 0.f, 0.f, 0.f};

  f16x8 bfU[NF], bfV[NF];
  const f16* wbase = Wf + ((size_t)fragRow0 * KSTEPS) * 512 + lane * 8;
#pragma unroll
  for (int ni = 0; ni < NF; ++ni)
    bfU[ni] = *(const f16x8*)(wbase + (size_t)(ni * KSTEPS + 0) * 512);
#pragma unroll
  for (int ni = 0; ni < NF; ++ni)
    bfV[ni] = *(const f16x8*)(wbase + (size_t)(ni * KSTEPS + 1) * 512);

#pragma unroll 1
  for (int ks = 0; ks < KSTEPS; ks += 2) {
    f16x8 af[4];
#pragma unroll
    for (int mi = 0; mi < 4; ++mi) {
      int r = mi * 16 + l16;
      af[mi] = *(const f16x8*)(actS + r * 512 + ((ks * 32 + lhi * 8) ^ ((r & 7) << 3)));
    }
#pragma unroll
    for (int mi = 0; mi < 4; ++mi)
#pragma unroll
      for (int ni = 0; ni < NF; ++ni)
        acc[mi][ni] = __builtin_amdgcn_mfma_f32_16x16x32_f16(bfU[ni], af[mi], acc[mi][ni], 0, 0, 0);
    if (ks + 2 < KSTEPS) {
#pragma unroll
      for (int ni = 0; ni < NF; ++ni)
        bfU[ni] = *(const f16x8*)(wbase + (size_t)(ni * KSTEPS + ks + 2) * 512);
    }
#pragma unroll
    for (int mi = 0; mi < 4; ++mi) {
      int r = mi * 16 + l16;
      af[mi] = *(const f16x8*)(actS + r * 512 + (((ks + 1) * 32 + lhi * 8) ^ ((r & 7) << 3)));
    }
#pragma unroll
    for (int mi = 0; mi < 4; ++mi)
#pragma unroll
      for (int ni = 0; ni < NF; ++ni)
        acc[mi][ni] = __builtin_amdgcn_mfma_f32_16x16x32_f16(bfV[ni], af[mi], acc[mi][ni], 0, 0, 0);
    if (ks + 3 < KSTEPS) {
#pragma unroll
      for (int ni = 0; ni < NF; ++ni)
        bfV[ni] = *(const f16x8*)(wbase + (size_t)(ni * KSTEPS + ks + 3) * 512);
    }
  }
}

// ---------------- fused MLP ----------------
// block = 64 rows, 8 waves; wave w owns cols [64w, 64w+64).
__global__ __launch_bounds__(512, 4) void fused_mlp(
    const float* __restrict__ x, const float* __restrict__ t,
    const float* __restrict__ cond, const float* __restrict__ tables,
    const f16* __restrict__ Wf0, const f16* __restrict__ Wf1,
    const f16* __restrict__ Wf2, const f16* __restrict__ Wf3,
    const float* __restrict__ b0, const float* __restrict__ b1,
    const float* __restrict__ b2, const float* __restrict__ b3,
    float* __restrict__ outp, Scales scl) {
  __shared__ f16 act[64 * 512];   // 64 KB, swizzled: elem = r*512 + (c ^ ((r&7)<<3))
  // L0 staging ALIASED into act (act unwritten until epi_act(b0)).
  f16* stg = act;                 // stg[p][kk][64][40] f16
#define STG(p, kk) (stg + (p) * 5120 + (kk) * 2560)

  const int tid = threadIdx.x;
  const int wave = tid >> 6, lane = tid & 63;
  const int l16 = lane & 15, lhi = lane >> 4;
  const int rowBase = blockIdx.x * 64;
  const int sr = tid >> 3, c8 = tid & 7;        // staging: 8 threads/row, 8 f16 each
  const int skk = c8 >> 2, sco = (c8 & 3) * 8;  // staged half + within-half col

  // ---- hash-grid encode: thread (sr,c8) computes levels 2c8, 2c8+1 of row sr.
  // Phase 1: address+weight gen. Phase 2: batched loads. Phase 3: accumulate.
  f16x8 er;   // staged for L0 step 12
  {
    int row = rowBase + sr;
    float c0 = cond[2 * row], c1 = cond[2 * row + 1], c2 = t[row];
    unsigned idx[2][8];
    float    wcw[2][8];
#pragma unroll
    for (int d = 0; d < 2; ++d) {
      int l = c8 * 2 + d;
      float s = scl.s[l];
      float xf0 = c0 * s, xf1 = c1 * s, xf2 = c2 * s;
      float xl0 = floorf(xf0), xl1 = floorf(xf1), xl2 = floorf(xf2);
      float w0 = xf0 - xl0, w1 = xf1 - xl1, w2 = xf2 - xl2;
      unsigned xi0 = (unsigned)xl0, xi1 = (unsigned)xl1, xi2 = (unsigned)xl2;
      unsigned h0 = xi0, h1 = xi1 * 2654435761u, h2 = xi2 * 805459861u;
      unsigned g0 = xi0 + 1u, g1 = (xi1 + 1u) * 2654435761u, g2 = (xi2 + 1u) * 805459861u;
#pragma unroll
      for (int c = 0; c < 8; ++c) {
        unsigned ax = (c >> 2) & 1u, ay = (c >> 1) & 1u, az = c & 1u;
        unsigned hh = (ax ? g0 : h0) ^ (ay ? g1 : h1) ^ (az ? g2 : h2);
        idx[d][c] = hh & T_MASK;
        wcw[d][c] = (ax ? w0 : 1.f - w0) * (ay ? w1 : 1.f - w1) * (az ? w2 : 1.f - w2);
      }
    }
    const f32x4* tl0 = (const f32x4*)tables + (size_t)(c8 * 2) * T_SIZE;
    f32x4 fv[2][8];
#pragma unroll
    for (int d = 0; d < 2; ++d)
#pragma unroll
      for (int c = 0; c < 8; ++c)
        fv[d][c] = tl0[(size_t)d * T_SIZE + idx[d][c]];
#pragma unroll
    for (int d = 0; d < 2; ++d) {
      float a0 = 0.f, a1 = 0.f, a2 = 0.f, a3 = 0.f;
#pragma unroll
      for (int c = 0; c < 8; ++c) {
        a0 += wcw[d][c] * fv[d][c].x; a1 += wcw[d][c] * fv[d][c].y;
        a2 += wcw[d][c] * fv[d][c].z; a3 += wcw[d][c] * fv[d][c].w;
      }
      er[d * 4 + 0] = (f16)a0; er[d * 4 + 1] = (f16)a1;
      er[d * 4 + 2] = (f16)a2; er[d * 4 + 3] = (f16)a3;
    }
  }

  f32x4 acc[4][4];
#pragma unroll
  for (int mi = 0; mi < 4; ++mi)
#pragma unroll
    for (int ni = 0; ni < 4; ++ni) acc[mi][ni] = (f32x4){0.f, 0.f, 0.f, 0.f};

  // ================= Layer 0: K = 832 = 13 steps x 64, x-prefetch dist 2 =======
  {
    const float* xrow = x + (size_t)(rowBase + sr) * 768 + c8 * 8;
    {  // stage step 0 (cols 0..63)
      f32x4 a = __builtin_nontemporal_load((const f32x4*)(xrow));
      f32x4 b = __builtin_nontemporal_load((const f32x4*)(xrow + 4));
      *(f16x8*)(STG(0, skk) + sr * 40 + sco) = cvt8(a, b);
    }
    // pA = data for step 1
    f32x4 pA0 = __builtin_nontemporal_load((const f32x4*)(xrow + 64));
    f32x4 pA1 = __builtin_nontemporal_load((const f32x4*)(xrow + 68));
    f32x4 pB0, pB1;
    const f16* wb = Wf0 + lane * 8;
    __syncthreads();

#pragma unroll 1
    for (int ks = 0; ks < 13; ++ks) {
      // issue load for step ks+2 (x data exists for steps 2..11)
      if (ks + 2 < 12) {
        pB0 = __builtin_nontemporal_load((const f32x4*)(xrow + (ks + 2) * 64));
        pB1 = __builtin_nontemporal_load((const f32x4*)(xrow + (ks + 2) * 64 + 4));
      }
      // weight frags for this step
      f16x8 bf[2][4];
#pragma unroll
      for (int kk = 0; kk < 2; ++kk)
#pragma unroll
        for (int ni = 0; ni < 4; ++ni)
          bf[kk][ni] = *(const f16x8*)(wb + (size_t)((wave * 4 + ni) * 26 + 2 * ks + kk) * 512);

      const f16* rb = stg + (ks & 1) * 5120;
#pragma unroll
      for (int kk = 0; kk < 2; ++kk)
#pragma unroll
        for (int mi = 0; mi < 4; ++mi) {
          f16x8 af = *(const f16x8*)(rb + kk * 2560 + (mi * 16 + l16) * 40 + lhi * 8);
#pragma unroll
          for (int ni = 0; ni < 4; ++ni)
            acc[mi][ni] = __builtin_amdgcn_mfma_f32_16x16x32_f16(bf[kk][ni], af, acc[mi][ni], 0, 0, 0);
        }

      if (ks < 11) {
        *(f16x8*)(STG((ks + 1) & 1, skk) + sr * 40 + sco) = cvt8(pA0, pA1);
        pA0 = pB0; pA1 = pB1;
      } else if (ks == 11) {
        *(f16x8*)(STG(0, skk) + sr * 40 + sco) = er;   // step 12 parity = 0
      }
      __syncthreads();
    }
  }

  // epilogue -> act (bias + silu). D-frag (swapped): act-row = mi*16+l16,
  // cols = wave*64 + ni*16 + lhi*4 .. +3
  auto epi_act = [&](const float* __restrict__ bias) {
    __syncthreads();
#pragma unroll
    for (int mi = 0; mi < 4; ++mi) {
      const int row = mi * 16 + l16;
#pragma unroll
      for (int ni = 0; ni < 4; ++ni) {
        const int col = wave * 64 + ni * 16 + lhi * 4;
        float4 bv = *(const float4*)(bias + col);
        f16x4 o;
        o[0] = (f16)silu_f(acc[mi][ni][0] + bv.x);
        o[1] = (f16)silu_f(acc[mi][ni][1] + bv.y);
        o[2] = (f16)silu_f(acc[mi][ni][2] + bv.z);
        o[3] = (f16)silu_f(acc[mi][ni][3] + bv.w);
        *(f16x4*)(act + row * 512 + (col ^ ((row & 7) << 3))) = o;
      }
    }
    __syncthreads();
  };
  epi_act(b0);

  // ================= Layers 1,2: K=512 =================
  kloop_dp<4, 16>(act, Wf1, wave * 4, l16, lhi, lane, acc); epi_act(b1);
  kloop_dp<4, 16>(act, Wf2, wave * 4, l16, lhi, lane, acc); epi_act(b2);

  // ================= Layer 3 pass A: cols 0..511 =================
  kloop_dp<4, 16>(act, Wf3, wave * 4, l16, lhi, lane, acc);
#pragma unroll
  for (int mi = 0; mi < 4; ++mi) {
    const size_t row = (size_t)(rowBase + mi * 16 + l16);
#pragma unroll
    for (int ni = 0; ni < 4; ++ni) {
      const int col = wave * 64 + ni * 16 + lhi * 4;
      float4 bv = *(const float4*)(b3 + col);
      f32x4 o = { acc[mi][ni][0] + bv.x, acc[mi][ni][1] + bv.y,
                  acc[mi][ni][2] + bv.z, acc[mi][ni][3] + bv.w };
      __builtin_nontemporal_store(o, (f32x4*)(outp + row * 768 + col));
    }
  }

  // ================= Layer 3 pass B: cols 512..767 =================
  kloop_dp<2, 16>(act, Wf3, 32 + wave * 2, l16, lhi, lane, acc);
#pragma unroll
  for (int mi = 0; mi < 4; ++mi) {
    const size_t row = (size_t)(rowBase + mi * 16 + l16);
#pragma unroll
    for (int ni = 0; ni < 2; ++ni) {
      const int col = 512 + wave * 32 + ni * 16 + lhi * 4;
      float4 bv = *(const float4*)(b3 + col);
      f32x4 o = { acc[mi][ni][0] + bv.x, acc[mi][ni][1] + bv.y,
                  acc[mi][ni][2] + bv.z, acc[mi][ni][3] + bv.w };
      __builtin_nontemporal_store(o, (f32x4*)(outp + row * 768 + col));
    }
  }
#undef STG
}

// ---------------- launch ----------------
extern "C" void kernel_launch(void* const* d_in, const int* in_sizes, int n_in,
                              void* d_out, int out_size, void* d_ws, size_t ws_size,
                              hipStream_t stream) {
  const float* t    = (const float*)d_in[0];
  const float* x    = (const float*)d_in[1];
  const float* cond = (const float*)d_in[2];
  const float* tab  = (const float*)d_in[3];
  const float* W0   = (const float*)d_in[4];
  const float* b0   = (const float*)d_in[5];
  const float* W1   = (const float*)d_in[6];
  const float* b1   = (const float*)d_in[7];
  const float* W2   = (const float*)d_in[8];
  const float* b2   = (const float*)d_in[9];
  const float* W3   = (const float*)d_in[10];
  const float* b3   = (const float*)d_in[11];
  float* out = (float*)d_out;
  (void)in_sizes; (void)n_in; (void)out_size; (void)ws_size;

  char* ws = (char*)d_ws;
  f16* Wf0 = (f16*)(ws + 0);            // 832*512*2 = 851968
  f16* Wf1 = (f16*)(ws + 851968);       // 524288
  f16* Wf2 = (f16*)(ws + 1376256);      // 524288
  f16* Wf3 = (f16*)(ws + 1900544);      // 786432 ; end 2686976

  wfrag<<<dim3(208), 256, 0, stream>>>(W0, Wf0, 832, 512);
  wfrag<<<dim3(128), 256, 0, stream>>>(W1, Wf1, 512, 512);
  wfrag<<<dim3(128), 256, 0, stream>>>(W2, Wf2, 512, 512);
  wfrag<<<dim3(192), 256, 0, stream>>>(W3, Wf3, 512, 768);

  Scales sc;
  {
    double growth = exp((log(512.0) - log(16.0)) / 15.0);
    for (int l = 0; l < 16; ++l) sc.s[l] = (float)floor(16.0 * pow(growth, (double)l));
  }

  fused_mlp<<<dim3(1024), 512, 0, stream>>>(x, t, cond, tab, Wf0, Wf1, Wf2, Wf3,
                                            b0, b1, b2, b3, out, sc);
}